// Round 4
// baseline (165.905 us; speedup 1.0000x reference)
//
#include <hip/hip_runtime.h>
#include <hip/hip_cooperative_groups.h>
namespace cg = cooperative_groups;

#define BB 4
#define SS 512
#define IND 32
#define HH 64
#define NCC 3

#define IPB 4                      // i's per block
#define NIC (SS / IPB)             // 128 i-chunks per batch
#define NBLK (BB * NIC)            // 512 blocks (needs only 2/CU co-resident)

// workspace layout (floats)
#define OFF_U   0
#define OFF_V   (OFF_U + BB*SS*HH)        // node-major [2048][64]
#define OFF_P   (OFF_V + BB*SS*HH)        // node-major [2048][32]
#define OFF_QT  (OFF_P + BB*SS*32)        // TRANSPOSED [32][2048]
#define OFF_SN  (OFF_QT + 32*BB*SS)       // [512][64]
#define OFF_SA  (OFF_SN + NBLK*HH)        // [512][64]
#define OFF_SH  (OFF_SA + NBLK*HH)        // [512][64]
#define OFF_SK  (OFF_SH + NBLK*HH)        // [512]

__device__ __forceinline__ float rl(float v, int l) {
    return __uint_as_float(__builtin_amdgcn_readlane(__float_as_uint(v), l));
}

__global__ __launch_bounds__(256, 4) void k_fused(
    const float* __restrict__ x,  const float* __restrict__ W1, const float* __restrict__ b1,
    const float* __restrict__ W2, const float* __restrict__ b2,
    const float* __restrict__ We1,const float* __restrict__ be1,
    const float* __restrict__ We2,const float* __restrict__ be2,
    const float* __restrict__ Wd1,const float* __restrict__ bd1,
    const float* __restrict__ wd2,const float* __restrict__ bd2,
    const float* __restrict__ Wc1,const float* __restrict__ bc1,
    const float* __restrict__ Wc2,const float* __restrict__ bc2,
    float* __restrict__ ws, float* __restrict__ out)
{
    cg::grid_group grid = cg::this_grid();

    float* U = ws + OFF_U;  float* V = ws + OFF_V;
    float* P = ws + OFF_P;  float* Qt = ws + OFF_QT;
    float* SN = ws + OFF_SN;
    float* SA = ws + OFF_SA;  float* SHo = ws + OFF_SH;  float* SK = ws + OFF_SK;

    __shared__ float redN[4][64], redA[4][64], redH[4][64];
    __shared__ float redS[128], redK[4];
    __shared__ float featL[128], c1L[32];      // ~4.3 KB total

    const int tid = threadIdx.x, wave = tid >> 6, lane = tid & 63;

    // ============ Phase A: node encoder (4 nodes/block, all waves) ============
    {
        const int node = blockIdx.x * 4 + wave;        // 0..2047
        float xv = (lane < IND) ? x[node * IND + lane] : 0.0f;
        float h1 = b1[lane];
        #pragma unroll
        for (int k = 0; k < IND; k++)
            h1 = fmaf(__shfl(xv, k, 64), W1[k * HH + lane], h1);
        h1 = fmaxf(h1, 0.0f);

        float nd = b2[lane];
        #pragma unroll 16
        for (int k = 0; k < HH; k++)
            nd = fmaf(__shfl(h1, k, 64), W2[k * HH + lane], nd);

        float uv = be1[lane];
        float vv = 0.0f;
        float pq = (lane < 32) ? bd1[lane] : 0.0f;
        const float* WdCol = (lane < 32) ? (Wd1 + lane) : (Wd1 + HH * 32 + (lane - 32));
        #pragma unroll 16
        for (int k = 0; k < HH; k++) {
            float s = __shfl(nd, k, 64);
            uv = fmaf(s, We1[k * HH + lane], uv);
            vv = fmaf(s, We1[(HH + k) * HH + lane], vv);
            pq = fmaf(s, WdCol[k * 32], pq);
        }
        U[node * HH + lane] = uv;
        V[node * HH + lane] = vv;
        if (lane < 32) P[node * 32 + lane] = pq;
        else           Qt[(lane - 32) * (BB * SS) + node] = pq;   // transposed
        redN[wave][lane] = nd;
    }
    __syncthreads();
    if (tid < 64)
        SN[blockIdx.x * 64 + tid] = (redN[0][tid] + redN[1][tid]) + (redN[2][tid] + redN[3][tid]);

    grid.sync();

    // ============ Phase B: all-pairs gate + gated accumulate ==================
    {
        const int b  = blockIdx.x >> 7;        // 128 blocks per batch
        const int ic = blockIdx.x & 127;
        const int i0 = ic * IPB;

        const float u0 = U[(b * SS + i0 + 0) * HH + lane];
        const float u1 = U[(b * SS + i0 + 1) * HH + lane];
        const float u2 = U[(b * SS + i0 + 2) * HH + lane];
        const float u3 = U[(b * SS + i0 + 3) * HH + lane];
        const float* Pb = P + (b * SS + i0) * 32;     // wave-uniform -> s_load
        const float bd2v = bd2[0];

        float sa = 0.0f, sh = 0.0f, sk = 0.0f;

        #pragma unroll
        for (int jc = 0; jc < 2; jc++) {
            const int jbase = b * SS + jc * 256 + wave * 64;   // this wave's 64 j's
            // ---- gate phase: lane <-> j, coalesced Qt reads ----
            float a0 = bd2v, a1 = bd2v, a2 = bd2v, a3 = bd2v;
            #pragma unroll
            for (int k = 0; k < 32; k++) {
                float qv = Qt[k * (BB * SS) + jbase + lane];
                float w  = wd2[k];
                a0 = fmaf(w, fmaxf(Pb[k]      + qv, 0.0f), a0);
                a1 = fmaf(w, fmaxf(Pb[32 + k] + qv, 0.0f), a1);
                a2 = fmaf(w, fmaxf(Pb[64 + k] + qv, 0.0f), a2);
                a3 = fmaf(w, fmaxf(Pb[96 + k] + qv, 0.0f), a3);
            }
            float g0 = 1.0f / (1.0f + __expf(-a0));
            float g1 = 1.0f / (1.0f + __expf(-a1));
            float g2 = 1.0f / (1.0f + __expf(-a2));
            float g3 = 1.0f / (1.0f + __expf(-a3));
            sk += (g0 + g1) + (g2 + g3);

            // ---- accumulate phase: lane <-> h component; gates via readlane ----
            const float* Vw = V + jbase * HH;
            #pragma unroll 16
            for (int joff = 0; joff < 64; joff++) {
                float vv = Vw[joff * HH + lane];
                float h0 = fmaxf(u0 + vv, 0.0f);
                float h1 = fmaxf(u1 + vv, 0.0f);
                float h2 = fmaxf(u2 + vv, 0.0f);
                float h3 = fmaxf(u3 + vv, 0.0f);
                sh += (h0 + h1) + (h2 + h3);
                sa = fmaf(rl(g0, joff), h0, sa);
                sa = fmaf(rl(g1, joff), h1, sa);
                sa = fmaf(rl(g2, joff), h2, sa);
                sa = fmaf(rl(g3, joff), h3, sa);
            }
        }

        redA[wave][lane] = sa;
        redH[wave][lane] = sh;
        #pragma unroll
        for (int off = 32; off; off >>= 1) sk += __shfl_xor(sk, off, 64);
        if (lane == 0) redK[wave] = sk;
        __syncthreads();
        if (tid < 64) {
            SA[blockIdx.x * 64 + tid]  = (redA[0][tid] + redA[1][tid]) + (redA[2][tid] + redA[3][tid]);
            SHo[blockIdx.x * 64 + tid] = (redH[0][tid] + redH[1][tid]) + (redH[2][tid] + redH[3][tid]);
        }
        if (tid == 64) SK[blockIdx.x] = (redK[0] + redK[1]) + (redK[2] + redK[3]);
    }

    grid.sync();

    // ============ Phase C: batch reduce + classifier (blocks 0-3) =============
    if (blockIdx.x < BB) {
        const int b = blockIdx.x;
        float sn = 0.0f, sa = 0.0f, sh = 0.0f;
        #pragma unroll 8
        for (int c = wave; c < NIC; c += 4) {          // 32 iters/thread
            int blk = b * NIC + c;
            sn += SN[blk * 64 + lane];
            sa += SA[blk * 64 + lane];
            sh += SHo[blk * 64 + lane];
        }
        if (tid < NIC) redS[tid] = SK[b * NIC + tid];
        redN[wave][lane] = sn; redA[wave][lane] = sa; redH[wave][lane] = sh;
        __syncthreads();

        if (wave == 0) {
            float snT = (redN[0][lane] + redN[1][lane]) + (redN[2][lane] + redN[3][lane]);
            float saT = (redA[0][lane] + redA[1][lane]) + (redA[2][lane] + redA[3][lane]);
            float shT = (redH[0][lane] + redH[1][lane]) + (redH[2][lane] + redH[3][lane]);
            float skp = redS[lane] + redS[64 + lane];
            #pragma unroll
            for (int off = 32; off; off >>= 1) skp += __shfl_xor(skp, off, 64);
            redA[0][lane] = saT;  redH[0][lane] = shT;

            float as = skp * be2[lane];
            float ts = (262144.0f - skp) * be2[lane];     // S*S - SK
            #pragma unroll 8
            for (int k = 0; k < HH; k++) {
                float w = We2[k * HH + lane];
                float sak = redA[0][k];
                as = fmaf(sak, w, as);
                ts = fmaf(redH[0][k] - sak, w, ts);
            }
            featL[lane]      = (snT + as) * (1.0f / 512.0f);
            featL[64 + lane] = ts * (1.0f / 512.0f);
        }
        __syncthreads();

        if (tid < 32) {
            float c1 = bc1[tid];
            #pragma unroll 8
            for (int k = 0; k < 128; k++)
                c1 = fmaf(featL[k], Wc1[k * 32 + tid], c1);
            c1L[tid] = fmaxf(c1, 0.0f);
        }
        __syncthreads();
        if (tid < NCC) {
            float o = bc2[tid];
            #pragma unroll
            for (int k = 0; k < 32; k++)
                o = fmaf(c1L[k], Wc2[k * NCC + tid], o);
            out[b * NCC + tid] = o;
        }
    }
}

extern "C" void kernel_launch(void* const* d_in, const int* in_sizes, int n_in,
                              void* d_out, int out_size, void* d_ws, size_t ws_size,
                              hipStream_t stream) {
    const float* x   = (const float*)d_in[0];
    const float* W1  = (const float*)d_in[1];
    const float* b1  = (const float*)d_in[2];
    const float* W2  = (const float*)d_in[3];
    const float* b2  = (const float*)d_in[4];
    const float* We1 = (const float*)d_in[5];
    const float* be1 = (const float*)d_in[6];
    const float* We2 = (const float*)d_in[7];
    const float* be2 = (const float*)d_in[8];
    const float* Wd1 = (const float*)d_in[9];
    const float* bd1 = (const float*)d_in[10];
    const float* wd2 = (const float*)d_in[11];
    const float* bd2 = (const float*)d_in[12];
    const float* Wc1 = (const float*)d_in[13];
    const float* bc1 = (const float*)d_in[14];
    const float* Wc2 = (const float*)d_in[15];
    const float* bc2 = (const float*)d_in[16];
    float* ws  = (float*)d_ws;
    float* out = (float*)d_out;

    void* args[] = {
        (void*)&x, (void*)&W1, (void*)&b1, (void*)&W2, (void*)&b2,
        (void*)&We1, (void*)&be1, (void*)&We2, (void*)&be2,
        (void*)&Wd1, (void*)&bd1, (void*)&wd2, (void*)&bd2,
        (void*)&Wc1, (void*)&bc1, (void*)&Wc2, (void*)&bc2,
        (void*)&ws, (void*)&out
    };
    hipLaunchCooperativeKernel((const void*)k_fused, dim3(NBLK), dim3(256),
                               args, 0, stream);
}

// Round 5
// 155.923 us; speedup vs baseline: 1.0640x; 1.0640x over previous
//
#include <hip/hip_runtime.h>

#define BB 4
#define SS 512
#define IND 32
#define HH 64
#define NCC 3

#define IPB 4                      // i's per block
#define NIC (SS / IPB)             // 128 i-chunks per batch
#define NBLK (BB * NIC)            // 512 blocks, 2/CU co-resident (coop-guaranteed)

// workspace layout (floats)
#define OFF_V    0                        // [2048][64] node-major
#define OFF_QT   (OFF_V + BB*SS*HH)       // [32][2048] transposed
#define OFF_SN   (OFF_QT + 32*BB*SS)      // [512][64]
#define OFF_SA   (OFF_SN + NBLK*HH)       // [512][64]
#define OFF_SH   (OFF_SA + NBLK*HH)       // [512][64]
#define OFF_SK   (OFF_SH + NBLK*HH)       // [512]
#define OFF_SYNC (OFF_SK + NBLK)          // uint cnt1; uint cnt2[4]

__device__ __forceinline__ float rl(float v, int l) {
    return __uint_as_float(__builtin_amdgcn_readlane(__float_as_uint(v), l));
}

__global__ __launch_bounds__(256, 4) void k_fused(
    const float* __restrict__ x,  const float* __restrict__ W1, const float* __restrict__ b1,
    const float* __restrict__ W2, const float* __restrict__ b2,
    const float* __restrict__ We1,const float* __restrict__ be1,
    const float* __restrict__ We2,const float* __restrict__ be2,
    const float* __restrict__ Wd1,const float* __restrict__ bd1,
    const float* __restrict__ wd2,const float* __restrict__ bd2,
    const float* __restrict__ Wc1,const float* __restrict__ bc1,
    const float* __restrict__ Wc2,const float* __restrict__ bc2,
    float* __restrict__ ws, float* __restrict__ out)
{
    float* V  = ws + OFF_V;   float* Qt = ws + OFF_QT;
    float* SN = ws + OFF_SN;  float* SA = ws + OFF_SA;
    float* SHo= ws + OFF_SH;  float* SK = ws + OFF_SK;
    unsigned int* syncc = (unsigned int*)(ws + OFF_SYNC);

    __shared__ float uL[4][64], pL[4][32];
    __shared__ float redN[4][64], redA[4][64], redH[4][64];
    __shared__ float redS[128], redK[4];
    __shared__ float featL[128], c1L[32];
    __shared__ int lastFlag;

    const int tid = threadIdx.x, wave = tid >> 6, lane = tid & 63;
    const int b  = blockIdx.x >> 7;        // 128 blocks per batch
    const int ic = blockIdx.x & 127;
    const int i0 = ic * IPB;

    // ============ Phase A: node encoder (4 nodes/block = this block's i rows) ==
    {
        const int node = blockIdx.x * 4 + wave;        // == b*512 + i0 + wave
        float xv = (lane < IND) ? x[node * IND + lane] : 0.0f;
        float h1 = b1[lane];
        #pragma unroll
        for (int k = 0; k < IND; k++)
            h1 = fmaf(__shfl(xv, k, 64), W1[k * HH + lane], h1);
        h1 = fmaxf(h1, 0.0f);

        float nd = b2[lane];
        #pragma unroll 16
        for (int k = 0; k < HH; k++)
            nd = fmaf(__shfl(h1, k, 64), W2[k * HH + lane], nd);

        float uv = be1[lane];
        float vv = 0.0f;
        float pq = (lane < 32) ? bd1[lane] : 0.0f;
        const float* WdCol = (lane < 32) ? (Wd1 + lane) : (Wd1 + HH * 32 + (lane - 32));
        #pragma unroll 16
        for (int k = 0; k < HH; k++) {
            float s = __shfl(nd, k, 64);
            uv = fmaf(s, We1[k * HH + lane], uv);
            vv = fmaf(s, We1[(HH + k) * HH + lane], vv);
            pq = fmaf(s, WdCol[k * 32], pq);
        }
        V[node * HH + lane] = vv;                       // cross-block data
        if (lane >= 32) Qt[(lane - 32) * (BB * SS) + node] = pq;   // cross-block
        uL[wave][lane] = uv;                            // block-local
        if (lane < 32) pL[wave][lane] = pq;             // block-local
        redN[wave][lane] = nd;
    }
    __syncthreads();
    if (tid < 64)
        SN[blockIdx.x * 64 + tid] = (redN[0][tid] + redN[1][tid]) + (redN[2][tid] + redN[3][tid]);

    // ============ Hand-rolled grid barrier (release V/Qt/SN -> all blocks) =====
    __threadfence();                                   // per-wave release (wb)
    __syncthreads();
    if (tid == 0) {
        __hip_atomic_fetch_add(&syncc[0], 1u, __ATOMIC_RELAXED, __HIP_MEMORY_SCOPE_AGENT);
        while (__hip_atomic_fetch_add(&syncc[0], 0u, __ATOMIC_RELAXED,
                                      __HIP_MEMORY_SCOPE_AGENT) < NBLK)
            __builtin_amdgcn_s_sleep(1);
        __threadfence();                               // acquire (inv) for the XCD
    }
    __syncthreads();

    // ============ Phase B: all-pairs gate + gated accumulate ==================
    {
        const float u0 = uL[0][lane], u1 = uL[1][lane];
        const float u2 = uL[2][lane], u3 = uL[3][lane];
        const float pk0 = pL[0][lane & 31], pk1 = pL[1][lane & 31];
        const float pk2 = pL[2][lane & 31], pk3 = pL[3][lane & 31];
        const float wv  = wd2[lane & 31];
        const float bd2v = bd2[0];

        float sa = 0.0f, sh = 0.0f, sk = 0.0f;

        #pragma unroll
        for (int jc = 0; jc < 2; jc++) {
            const int jbase = b * SS + jc * 256 + wave * 64;   // this wave's 64 j's
            // ---- gate: lane <-> j; P/wd2 broadcast via readlane (literal k) ----
            float a0 = bd2v, a1 = bd2v, a2 = bd2v, a3 = bd2v;
            #pragma unroll
            for (int k = 0; k < 32; k++) {
                float qv = Qt[k * (BB * SS) + jbase + lane];
                float w  = rl(wv, k);
                a0 = fmaf(w, fmaxf(rl(pk0, k) + qv, 0.0f), a0);
                a1 = fmaf(w, fmaxf(rl(pk1, k) + qv, 0.0f), a1);
                a2 = fmaf(w, fmaxf(rl(pk2, k) + qv, 0.0f), a2);
                a3 = fmaf(w, fmaxf(rl(pk3, k) + qv, 0.0f), a3);
            }
            float g0 = 1.0f / (1.0f + __expf(-a0));
            float g1 = 1.0f / (1.0f + __expf(-a1));
            float g2 = 1.0f / (1.0f + __expf(-a2));
            float g3 = 1.0f / (1.0f + __expf(-a3));
            sk += (g0 + g1) + (g2 + g3);

            // ---- accumulate: lane <-> h component; gates via readlane ----
            const float* Vw = V + jbase * HH;
            #pragma unroll 16
            for (int joff = 0; joff < 64; joff++) {
                float vv = Vw[joff * HH + lane];
                float h0 = fmaxf(u0 + vv, 0.0f);
                float h1 = fmaxf(u1 + vv, 0.0f);
                float h2 = fmaxf(u2 + vv, 0.0f);
                float h3 = fmaxf(u3 + vv, 0.0f);
                sh += (h0 + h1) + (h2 + h3);
                sa = fmaf(rl(g0, joff), h0, sa);
                sa = fmaf(rl(g1, joff), h1, sa);
                sa = fmaf(rl(g2, joff), h2, sa);
                sa = fmaf(rl(g3, joff), h3, sa);
            }
        }

        redA[wave][lane] = sa;
        redH[wave][lane] = sh;
        #pragma unroll
        for (int off = 32; off; off >>= 1) sk += __shfl_xor(sk, off, 64);
        if (lane == 0) redK[wave] = sk;
        __syncthreads();
        // wave 0 does ALL global partial stores (single-wave fence suffices)
        if (tid < 64) {
            SA[blockIdx.x * 64 + tid]  = (redA[0][tid] + redA[1][tid]) + (redA[2][tid] + redA[3][tid]);
            SHo[blockIdx.x * 64 + tid] = (redH[0][tid] + redH[1][tid]) + (redH[2][tid] + redH[3][tid]);
            if (tid == 0)
                SK[blockIdx.x] = (redK[0] + redK[1]) + (redK[2] + redK[3]);
            __threadfence();                           // release wave-0 stores
        }
        __syncthreads();
        if (tid == 0) {
            unsigned int old = __hip_atomic_fetch_add(&syncc[1 + b], 1u,
                                   __ATOMIC_RELAXED, __HIP_MEMORY_SCOPE_AGENT);
            lastFlag = (old == (unsigned)(NIC - 1));
        }
        __syncthreads();
    }

    // ============ Phase C: last block per batch reduces + classifies ==========
    if (lastFlag) {
        if (tid == 0) __threadfence();                 // acquire partials
        __syncthreads();

        float sn = 0.0f, sa = 0.0f, sh = 0.0f;
        #pragma unroll 8
        for (int c = wave; c < NIC; c += 4) {          // 32 iters/thread
            int blk = b * NIC + c;
            sn += SN[blk * 64 + lane];
            sa += SA[blk * 64 + lane];
            sh += SHo[blk * 64 + lane];
        }
        if (tid < NIC) redS[tid] = SK[b * NIC + tid];
        redN[wave][lane] = sn; redA[wave][lane] = sa; redH[wave][lane] = sh;
        __syncthreads();

        if (wave == 0) {
            float snT = (redN[0][lane] + redN[1][lane]) + (redN[2][lane] + redN[3][lane]);
            float saT = (redA[0][lane] + redA[1][lane]) + (redA[2][lane] + redA[3][lane]);
            float shT = (redH[0][lane] + redH[1][lane]) + (redH[2][lane] + redH[3][lane]);
            float skp = redS[lane] + redS[64 + lane];
            #pragma unroll
            for (int off = 32; off; off >>= 1) skp += __shfl_xor(skp, off, 64);
            redA[0][lane] = saT;  redH[0][lane] = shT;

            float as = skp * be2[lane];
            float ts = (262144.0f - skp) * be2[lane];     // S*S - SK
            #pragma unroll 8
            for (int k = 0; k < HH; k++) {
                float w = We2[k * HH + lane];
                float sak = redA[0][k];
                as = fmaf(sak, w, as);
                ts = fmaf(redH[0][k] - sak, w, ts);
            }
            featL[lane]      = (snT + as) * (1.0f / 512.0f);
            featL[64 + lane] = ts * (1.0f / 512.0f);
        }
        __syncthreads();

        if (tid < 32) {
            float c1 = bc1[tid];
            #pragma unroll 8
            for (int k = 0; k < 128; k++)
                c1 = fmaf(featL[k], Wc1[k * 32 + tid], c1);
            c1L[tid] = fmaxf(c1, 0.0f);
        }
        __syncthreads();
        if (tid < NCC) {
            float o = bc2[tid];
            #pragma unroll
            for (int k = 0; k < 32; k++)
                o = fmaf(c1L[k], Wc2[k * NCC + tid], o);
            out[b * NCC + tid] = o;
        }
    }
}

extern "C" void kernel_launch(void* const* d_in, const int* in_sizes, int n_in,
                              void* d_out, int out_size, void* d_ws, size_t ws_size,
                              hipStream_t stream) {
    const float* x   = (const float*)d_in[0];
    const float* W1  = (const float*)d_in[1];
    const float* b1  = (const float*)d_in[2];
    const float* W2  = (const float*)d_in[3];
    const float* b2  = (const float*)d_in[4];
    const float* We1 = (const float*)d_in[5];
    const float* be1 = (const float*)d_in[6];
    const float* We2 = (const float*)d_in[7];
    const float* be2 = (const float*)d_in[8];
    const float* Wd1 = (const float*)d_in[9];
    const float* bd1 = (const float*)d_in[10];
    const float* wd2 = (const float*)d_in[11];
    const float* bd2 = (const float*)d_in[12];
    const float* Wc1 = (const float*)d_in[13];
    const float* bc1 = (const float*)d_in[14];
    const float* Wc2 = (const float*)d_in[15];
    const float* bc2 = (const float*)d_in[16];
    float* ws  = (float*)d_ws;
    float* out = (float*)d_out;

    // zero the sync counters (ws is poisoned 0xAA before timing, left dirty after)
    hipMemsetAsync((char*)d_ws + OFF_SYNC * sizeof(float), 0, 32, stream);

    void* args[] = {
        (void*)&x, (void*)&W1, (void*)&b1, (void*)&W2, (void*)&b2,
        (void*)&We1, (void*)&be1, (void*)&We2, (void*)&be2,
        (void*)&Wd1, (void*)&bd1, (void*)&wd2, (void*)&bd2,
        (void*)&Wc1, (void*)&bc1, (void*)&Wc2, (void*)&bc2,
        (void*)&ws, (void*)&out
    };
    hipLaunchCooperativeKernel((const void*)k_fused, dim3(NBLK), dim3(256),
                               args, 0, stream);
}

// Round 6
// 50.633 us; speedup vs baseline: 3.2766x; 3.0795x over previous
//
#include <hip/hip_runtime.h>

#define BB 4
#define SS 512
#define IND 32
#define HH 64
#define NCC 3

#define IPB 4                      // i's per k2 block
#define NIC (SS / IPB)             // 128 blocks per batch
#define NBLK (BB * NIC)            // 512 blocks

// workspace layout (floats)
#define OFF_U    0                        // [2048][64]
#define OFF_V    (OFF_U + BB*SS*HH)       // [2048][64]
#define OFF_P    (OFF_V + BB*SS*HH)       // [2048][32]
#define OFF_QT   (OFF_P + BB*SS*32)       // [32][2048] transposed
#define OFF_SN   (OFF_QT + 32*BB*SS)      // [512][64]  256B/row per block
#define OFF_SA   (OFF_SN + NBLK*HH)       // [512][64]
#define OFF_SH   (OFF_SA + NBLK*HH)       // [512][64]
#define OFF_SKP  (OFF_SH + NBLK*HH)       // [512*16] stride 64B (no false sharing)
#define OFF_SYNC (OFF_SKP + NBLK*16)      // uint ticket[4]

__device__ __forceinline__ float rl(float v, int l) {
    return __uint_as_float(__builtin_amdgcn_readlane(__float_as_uint(v), l));
}

__global__ __launch_bounds__(256) void k_nodes(
    const float* __restrict__ x,  const float* __restrict__ W1, const float* __restrict__ b1,
    const float* __restrict__ W2, const float* __restrict__ b2,
    const float* __restrict__ We1,const float* __restrict__ be1,
    const float* __restrict__ Wd1,const float* __restrict__ bd1,
    float* __restrict__ ws)
{
    float* U = ws + OFF_U;  float* V = ws + OFF_V;
    float* P = ws + OFF_P;  float* Qt = ws + OFF_QT;
    float* SN = ws + OFF_SN;
    __shared__ float sn_lds[4][64];
    const int tid = threadIdx.x, wave = tid >> 6, lane = tid & 63;
    const int node = blockIdx.x * 4 + wave;   // 2048 nodes

    float xv = (lane < IND) ? x[node * IND + lane] : 0.0f;
    float h1 = b1[lane];
    #pragma unroll
    for (int k = 0; k < IND; k++)
        h1 = fmaf(__shfl(xv, k, 64), W1[k * HH + lane], h1);
    h1 = fmaxf(h1, 0.0f);

    float nd = b2[lane];
    #pragma unroll 16
    for (int k = 0; k < HH; k++)
        nd = fmaf(__shfl(h1, k, 64), W2[k * HH + lane], nd);

    float uv = be1[lane];
    float vv = 0.0f;
    float pq = (lane < 32) ? bd1[lane] : 0.0f;
    const float* WdCol = (lane < 32) ? (Wd1 + lane) : (Wd1 + HH * 32 + (lane - 32));
    #pragma unroll 16
    for (int k = 0; k < HH; k++) {
        float s = __shfl(nd, k, 64);
        uv = fmaf(s, We1[k * HH + lane], uv);
        vv = fmaf(s, We1[(HH + k) * HH + lane], vv);
        pq = fmaf(s, WdCol[k * 32], pq);
    }
    U[node * HH + lane] = uv;
    V[node * HH + lane] = vv;
    if (lane < 32) P[node * 32 + lane] = pq;
    else           Qt[(lane - 32) * (BB * SS) + node] = pq;   // transposed

    sn_lds[wave][lane] = nd;
    __syncthreads();
    if (tid < 64)
        SN[blockIdx.x * 64 + tid] = (sn_lds[0][tid] + sn_lds[1][tid]) + (sn_lds[2][tid] + sn_lds[3][tid]);
}

__global__ __launch_bounds__(256) void k_pairs(
    const float* __restrict__ wd2, const float* __restrict__ bd2,
    const float* __restrict__ We2, const float* __restrict__ be2,
    const float* __restrict__ Wc1, const float* __restrict__ bc1,
    const float* __restrict__ Wc2, const float* __restrict__ bc2,
    float* __restrict__ ws, float* __restrict__ out)
{
    const float* U = ws + OFF_U;   const float* V  = ws + OFF_V;
    const float* P = ws + OFF_P;   const float* Qt = ws + OFF_QT;
    const float* SN = ws + OFF_SN;
    float* SA = ws + OFF_SA;  float* SHo = ws + OFF_SH;  float* SKp = ws + OFF_SKP;
    unsigned int* tick = (unsigned int*)(ws + OFF_SYNC);

    __shared__ float4 gs[4][64];               // per-wave gate rows
    __shared__ float redN[4][64], redA[4][64], redH[4][64], redK[4];
    __shared__ float redS[128], featL[128], c1L[32];
    __shared__ int lastFlag;

    const int tid = threadIdx.x, wave = tid >> 6, lane = tid & 63;
    const int b  = blockIdx.x >> 7;            // 128 blocks per batch
    const int ic = blockIdx.x & 127;
    const int i0 = ic * IPB;

    // ---- block inputs (written by k1; kernel boundary = global barrier) ----
    const float u0 = U[(b * SS + i0 + 0) * HH + lane];
    const float u1 = U[(b * SS + i0 + 1) * HH + lane];
    const float u2 = U[(b * SS + i0 + 2) * HH + lane];
    const float u3 = U[(b * SS + i0 + 3) * HH + lane];
    const float pk0 = P[(b * SS + i0 + 0) * 32 + (lane & 31)];
    const float pk1 = P[(b * SS + i0 + 1) * 32 + (lane & 31)];
    const float pk2 = P[(b * SS + i0 + 2) * 32 + (lane & 31)];
    const float pk3 = P[(b * SS + i0 + 3) * 32 + (lane & 31)];
    const float wv  = wd2[lane & 31];
    const float bd2v = bd2[0];

    float sa = 0.0f, sh = 0.0f, sk = 0.0f;

    #pragma unroll
    for (int jc = 0; jc < 2; jc++) {
        const int jbase = b * SS + jc * 256 + wave * 64;   // this wave's 64 j's
        // ---- gate: lane <-> j; P/wd2 broadcast via readlane (literal k) ----
        float a0 = bd2v, a1 = bd2v, a2 = bd2v, a3 = bd2v;
        #pragma unroll
        for (int k = 0; k < 32; k++) {
            float qv = Qt[k * (BB * SS) + jbase + lane];
            float w  = rl(wv, k);
            a0 = fmaf(w, fmaxf(rl(pk0, k) + qv, 0.0f), a0);
            a1 = fmaf(w, fmaxf(rl(pk1, k) + qv, 0.0f), a1);
            a2 = fmaf(w, fmaxf(rl(pk2, k) + qv, 0.0f), a2);
            a3 = fmaf(w, fmaxf(rl(pk3, k) + qv, 0.0f), a3);
        }
        float g0 = 1.0f / (1.0f + __expf(-a0));
        float g1 = 1.0f / (1.0f + __expf(-a1));
        float g2 = 1.0f / (1.0f + __expf(-a2));
        float g3 = 1.0f / (1.0f + __expf(-a3));
        sk += (g0 + g1) + (g2 + g3);
        gs[wave][lane] = make_float4(g0, g1, g2, g3);      // ds_write_b128

        // ---- accumulate: lane <-> h comp; gates via uniform ds_read_b128 ----
        const float* Vw = V + jbase * HH;
        #pragma unroll 16
        for (int joff = 0; joff < 64; joff++) {
            float vv = Vw[joff * HH + lane];               // coalesced, L2-resident
            float4 g4 = gs[wave][joff];                    // broadcast read
            float h0 = fmaxf(u0 + vv, 0.0f);
            float h1 = fmaxf(u1 + vv, 0.0f);
            float h2 = fmaxf(u2 + vv, 0.0f);
            float h3 = fmaxf(u3 + vv, 0.0f);
            sh += (h0 + h1) + (h2 + h3);
            sa = fmaf(g4.x, h0, sa);
            sa = fmaf(g4.y, h1, sa);
            sa = fmaf(g4.z, h2, sa);
            sa = fmaf(g4.w, h3, sa);
        }
    }

    redA[wave][lane] = sa;
    redH[wave][lane] = sh;
    #pragma unroll
    for (int off = 32; off; off >>= 1) sk += __shfl_xor(sk, off, 64);
    if (lane == 0) redK[wave] = sk;
    __syncthreads();

    // ---- wave 0: store partials, release-fence, ticket ----
    if (tid < 64) {
        SA[blockIdx.x * 64 + tid]  = (redA[0][tid] + redA[1][tid]) + (redA[2][tid] + redA[3][tid]);
        SHo[blockIdx.x * 64 + tid] = (redH[0][tid] + redH[1][tid]) + (redH[2][tid] + redH[3][tid]);
        if (tid == 0)
            SKp[blockIdx.x * 16] = (redK[0] + redK[1]) + (redK[2] + redK[3]);
        __threadfence();                        // release partials (wbl2), wave 0 only
        if (tid == 0) {
            unsigned int old = __hip_atomic_fetch_add(&tick[b], 1u,
                                   __ATOMIC_RELAXED, __HIP_MEMORY_SCOPE_AGENT);
            lastFlag = ((old & 127u) == 127u);  // works for ANY initial counter value
        }
    }
    __syncthreads();

    // ---- last block of each batch: reduce + classifier ----
    if (lastFlag) {
        if (tid == 0) __threadfence();          // acquire (inv L1/L2 of this CU's XCD)
        __syncthreads();

        float sn = 0.0f, saT = 0.0f, shT = 0.0f;
        #pragma unroll 8
        for (int c = wave; c < NIC; c += 4) {   // 32 iters/thread
            int blk = b * NIC + c;
            sn  += SN[blk * 64 + lane];
            saT += SA[blk * 64 + lane];
            shT += SHo[blk * 64 + lane];
        }
        if (tid < NIC) redS[tid] = SKp[(b * NIC + tid) * 16];
        redN[wave][lane] = sn; redA[wave][lane] = saT; redH[wave][lane] = shT;
        __syncthreads();

        if (wave == 0) {
            float snT = (redN[0][lane] + redN[1][lane]) + (redN[2][lane] + redN[3][lane]);
            float saF = (redA[0][lane] + redA[1][lane]) + (redA[2][lane] + redA[3][lane]);
            float shF = (redH[0][lane] + redH[1][lane]) + (redH[2][lane] + redH[3][lane]);
            float skp = redS[lane] + redS[64 + lane];
            #pragma unroll
            for (int off = 32; off; off >>= 1) skp += __shfl_xor(skp, off, 64);
            redA[0][lane] = saF;  redH[0][lane] = shF;

            float as = skp * be2[lane];
            float ts = (262144.0f - skp) * be2[lane];     // S*S - SK
            #pragma unroll 8
            for (int k = 0; k < HH; k++) {
                float w = We2[k * HH + lane];
                float sak = redA[0][k];
                as = fmaf(sak, w, as);
                ts = fmaf(redH[0][k] - sak, w, ts);
            }
            featL[lane]      = (snT + as) * (1.0f / 512.0f);
            featL[64 + lane] = ts * (1.0f / 512.0f);
        }
        __syncthreads();

        if (tid < 32) {
            float c1 = bc1[tid];
            #pragma unroll 8
            for (int k = 0; k < 128; k++)
                c1 = fmaf(featL[k], Wc1[k * 32 + tid], c1);
            c1L[tid] = fmaxf(c1, 0.0f);
        }
        __syncthreads();
        if (tid < NCC) {
            float o = bc2[tid];
            #pragma unroll
            for (int k = 0; k < 32; k++)
                o = fmaf(c1L[k], Wc2[k * NCC + tid], o);
            out[b * NCC + tid] = o;
        }
    }
}

extern "C" void kernel_launch(void* const* d_in, const int* in_sizes, int n_in,
                              void* d_out, int out_size, void* d_ws, size_t ws_size,
                              hipStream_t stream) {
    const float* x   = (const float*)d_in[0];
    const float* W1  = (const float*)d_in[1];
    const float* b1  = (const float*)d_in[2];
    const float* W2  = (const float*)d_in[3];
    const float* b2  = (const float*)d_in[4];
    const float* We1 = (const float*)d_in[5];
    const float* be1 = (const float*)d_in[6];
    const float* We2 = (const float*)d_in[7];
    const float* be2 = (const float*)d_in[8];
    const float* Wd1 = (const float*)d_in[9];
    const float* bd1 = (const float*)d_in[10];
    const float* wd2 = (const float*)d_in[11];
    const float* bd2 = (const float*)d_in[12];
    const float* Wc1 = (const float*)d_in[13];
    const float* bc1 = (const float*)d_in[14];
    const float* Wc2 = (const float*)d_in[15];
    const float* bc2 = (const float*)d_in[16];
    float* ws  = (float*)d_ws;
    float* out = (float*)d_out;

    k_nodes<<<dim3(NBLK), dim3(256), 0, stream>>>(x, W1, b1, W2, b2, We1, be1, Wd1, bd1, ws);
    k_pairs<<<dim3(NBLK), dim3(256), 0, stream>>>(wd2, bd2, We2, be2, Wc1, bc1, Wc2, bc2, ws, out);
}